// Round 1
// baseline (5685.415 us; speedup 1.0000x reference)
//
#include <hip/hip_runtime.h>
#include <math.h>

#define N_NODES 100000
#define N_EDGES 1600000

static constexpr int GEMM_GRID = (N_NODES + 63) / 64;     // 1563
static constexpr int NODE_GRID = (N_NODES + 255) / 256;   // 391
static constexpr unsigned M_INIT = 0x007FFFFFu;           // fmap(-inf)

__device__ __forceinline__ float lrelu(float v, float s){ return v >= 0.f ? v : v*s; }

__device__ __forceinline__ unsigned fmap(float v){
    unsigned u = __float_as_uint(v);
    return (u & 0x80000000u) ? ~u : (u | 0x80000000u);
}

// ---------------- generic row-block GEMM: C = act(A@B + bias) ----------------
// A [N_NODES, K] stride K (may alias C for in-place), B [K, M] row-major.
// Block owns 64 rows and ALL M columns (M <= 64*NCT) -> in-place safe.
template<int NCT>
__global__ __launch_bounds__(256) void gemm_rows(
    const float* A, const float* __restrict__ B, const float* __restrict__ bias,
    float* C, int K, int M, int OS, float slope)
{
    constexpr int BNtot = 64 * NCT;
    __shared__ float At[16 * 68];
    __shared__ float Bt[16 * BNtot];
    const int t  = threadIdx.x;
    const int r0 = blockIdx.x * 64;
    const int tx = t & 15, ty = t >> 4;

    float acc[4][4 * NCT];
#pragma unroll
    for (int i = 0; i < 4; i++)
#pragma unroll
        for (int j = 0; j < 4 * NCT; j++) acc[i][j] = 0.f;

    for (int k0 = 0; k0 < K; k0 += 16) {
        { // stage A (transposed, stride 68)
            int r = t >> 2, kq = t & 3;
            float4 v = make_float4(0.f, 0.f, 0.f, 0.f);
            int row = r0 + r, kk = k0 + kq * 4;
            if (row < N_NODES && kk < K)
                v = *(const float4*)(A + (long)row * K + kk);
            At[(kq*4+0)*68 + r] = v.x;
            At[(kq*4+1)*68 + r] = v.y;
            At[(kq*4+2)*68 + r] = v.z;
            At[(kq*4+3)*68 + r] = v.w;
        }
#pragma unroll
        for (int i = 0; i < NCT; i++) { // stage B
            int idx = i * 256 + t;
            constexpr int fpr = BNtot / 4;
            int kk = idx / fpr, mq = idx % fpr;
            float4 v = make_float4(0.f, 0.f, 0.f, 0.f);
            if (k0 + kk < K && mq * 4 < M)
                v = *(const float4*)(B + (long)(k0 + kk) * M + mq * 4);
            *(float4*)(Bt + kk * BNtot + mq * 4) = v;
        }
        __syncthreads();
#pragma unroll
        for (int kk = 0; kk < 16; kk++) {
            float4 av = *(const float4*)(At + kk * 68 + ty * 4);
            float a_[4] = {av.x, av.y, av.z, av.w};
#pragma unroll
            for (int ct = 0; ct < NCT; ct++) {
                float4 bv = *(const float4*)(Bt + kk * BNtot + ct * 64 + tx * 4);
                float b_[4] = {bv.x, bv.y, bv.z, bv.w};
#pragma unroll
                for (int i = 0; i < 4; i++)
#pragma unroll
                    for (int j = 0; j < 4; j++)
                        acc[i][ct*4+j] += a_[i] * b_[j];
            }
        }
        __syncthreads();
    }
#pragma unroll
    for (int i = 0; i < 4; i++) {
        int row = r0 + ty * 4 + i;
        if (row >= N_NODES) continue;
#pragma unroll
        for (int ct = 0; ct < NCT; ct++)
#pragma unroll
            for (int j = 0; j < 4; j++) {
                int col = ct * 64 + tx * 4 + j;
                if (col < M) {
                    float v = acc[i][ct*4+j];
                    if (bias) v += bias[col];
                    C[(long)row * OS + col] = lrelu(v, slope);
                }
            }
    }
}

// ---------------- BN stats (sum, sumsq) for channels [lo, lo+W) ----------------
__global__ void bn_stats(const float* __restrict__ X, int S, int lo, int W,
                         float* __restrict__ gsum, float* __restrict__ gsq)
{
    int RP = 256 / W;
    int active = RP * W;
    int t = threadIdx.x;
    float s = 0.f, q = 0.f;
    if (t < active) {
        int ch = t % W, ro = t / W;
        for (long row = (long)blockIdx.x * RP + ro; row < N_NODES; row += (long)gridDim.x * RP) {
            float v = X[row * S + lo + ch];
            s += v; q += v * v;
        }
    }
    __shared__ float ls[256];
    ls[t] = s; __syncthreads();
    if (t < W) {
        float a = 0.f;
        for (int k = t; k < active; k += W) a += ls[k];
        atomicAdd(gsum + lo + t, a);
    }
    __syncthreads();
    ls[t] = q; __syncthreads();
    if (t < W) {
        float a = 0.f;
        for (int k = t; k < active; k += W) a += ls[k];
        atomicAdd(gsq + lo + t, a);
    }
}

__global__ void bn_finalize(const float* __restrict__ gsum, const float* __restrict__ gsq,
                            const float* __restrict__ gamma, const float* __restrict__ beta,
                            float* __restrict__ Aab, float* __restrict__ Bab, int C)
{
    int c = threadIdx.x;
    if (c >= C) return;
    float mu  = gsum[c] * (1.f / N_NODES);
    float var = gsq[c]  * (1.f / N_NODES) - mu * mu;
    float A = rsqrtf(var + 1e-5f) * gamma[c];
    Aab[c] = A;
    Bab[c] = beta[c] - mu * A;
}

// ---------------- densenet layer: leaky(BN(x)) @ W^T appended at col C -------
__global__ __launch_bounds__(256) void dense_conv(
    float* X, int S, int C,
    const float* __restrict__ W, int WS,
    const float* __restrict__ Aab, const float* __restrict__ Bab,
    float* __restrict__ gsum, float* __restrict__ gsq)
{
    long n = (long)blockIdx.x * 256 + threadIdx.x;
    bool valid = (n < N_NODES);
    float acc[12];
#pragma unroll
    for (int g = 0; g < 12; g++) acc[g] = 0.f;
    if (valid) {
        const float* xr = X + n * S;
        for (int cq = 0; cq < C; cq += 4) {
            float4 xv = *(const float4*)(xr + cq);
            float xs[4] = {xv.x, xv.y, xv.z, xv.w};
#pragma unroll
            for (int j = 0; j < 4; j++) {
                int ch = cq + j;
                float v = Aab[ch] * xs[j] + Bab[ch];
                v = (v >= 0.f) ? v : 0.01f * v;
#pragma unroll
                for (int g = 0; g < 12; g++)
                    acc[g] += v * W[g * WS + ch];
            }
        }
        float* xo = X + n * S + C;
#pragma unroll
        for (int g = 0; g < 12; g++) xo[g] = acc[g];
    }
    // fused stats for the 12 new channels (used by the next layer's BN)
    float sv[12], qv[12];
#pragma unroll
    for (int g = 0; g < 12; g++) { float v = valid ? acc[g] : 0.f; sv[g] = v; qv[g] = v * v; }
#pragma unroll
    for (int msk = 1; msk < 64; msk <<= 1) {
#pragma unroll
        for (int g = 0; g < 12; g++) {
            sv[g] += __shfl_xor(sv[g], msk, 64);
            qv[g] += __shfl_xor(qv[g], msk, 64);
        }
    }
    if ((threadIdx.x & 63) == 0) {
#pragma unroll
        for (int g = 0; g < 12; g++) {
            atomicAdd(gsum + C + g, sv[g]);
            atomicAdd(gsq  + C + g, qv[g]);
        }
    }
}

// ---------------- GAT ----------------
__global__ void gat_scores(const float* __restrict__ H, int F, const float* __restrict__ a,
                           float* __restrict__ sd, float* __restrict__ ss)
{
    long n = (long)blockIdx.x * 256 + threadIdx.x;
    if (n >= N_NODES) return;
    const float* h = H + n * F;
    float s1 = 0.f, s2 = 0.f;
    for (int f = 0; f < F; f += 4) {
        float4 hv = *(const float4*)(h + f);
        s1 += hv.x*a[f] + hv.y*a[f+1] + hv.z*a[f+2] + hv.w*a[f+3];
        s2 += hv.x*a[F+f] + hv.y*a[F+f+1] + hv.z*a[F+f+2] + hv.w*a[F+f+3];
    }
    sd[n] = s1; ss[n] = s2;
}

__global__ void gat_init(unsigned* __restrict__ m_u, float* __restrict__ den)
{
    long n = (long)blockIdx.x * 256 + threadIdx.x;
    if (n >= N_NODES) return;
    m_u[n] = M_INIT;
    den[n] = 0.f;
}

__global__ void gat_edge1(const int* __restrict__ src, const int* __restrict__ dst,
                          const float* __restrict__ sd, const float* __restrict__ ss,
                          float* __restrict__ ev, unsigned* __restrict__ m_u)
{
    for (long e = (long)blockIdx.x * 256 + threadIdx.x; e < N_EDGES; e += (long)gridDim.x * 256) {
        int d = dst[e], s = src[e];
        float v = sd[d] + ss[s];
        v = (v >= 0.f) ? v : 0.2f * v;
        ev[e] = v;
        atomicMax(m_u + d, fmap(v));
    }
}

__global__ void gat_fixm(unsigned* __restrict__ m_u)
{
    long n = (long)blockIdx.x * 256 + threadIdx.x;
    if (n >= N_NODES) return;
    unsigned u = m_u[n];
    float m;
    if (u == M_INIT) m = 0.f;   // empty segment: where(isfinite(m), m, 0)
    else m = (u & 0x80000000u) ? __uint_as_float(u ^ 0x80000000u) : __uint_as_float(~u);
    m_u[n] = __float_as_uint(m);
}

__global__ void gat_edge2(const int* __restrict__ dst, const float* __restrict__ ev,
                          const float* __restrict__ mf, float* __restrict__ exv,
                          float* __restrict__ den)
{
    for (long e = (long)blockIdx.x * 256 + threadIdx.x; e < N_EDGES; e += (long)gridDim.x * 256) {
        int d = dst[e];
        float x = __expf(ev[e] - mf[d]);
        exv[e] = x;
        atomicAdd(den + d, x);
    }
}

// wave per node: out[n,:F] = sum_e alpha_e * H[src_e,:F] + bias
__global__ __launch_bounds__(256) void gat_aggregate(
    const int* __restrict__ src, const float* __restrict__ exv,
    const float* __restrict__ den, const int* __restrict__ rstart,
    const int* __restrict__ csr, const float* __restrict__ H, int F,
    const float* __restrict__ bias, float* __restrict__ out, int OS)
{
    int wid  = threadIdx.x >> 6;
    int lane = threadIdx.x & 63;
    long node = (long)blockIdx.x * 4 + wid;
    if (node >= N_NODES) return;
    int st = rstart[node], en = rstart[node + 1];
    float invden = 1.f / (den[node] + 1e-16f);
    float acc = 0.f;
    for (int base = st; base < en; base += 64) {
        int cnt = min(64, en - base);
        float al = 0.f; int sj = 0;
        if (lane < cnt) {
            int eid = csr[base + lane];
            al = exv[eid] * invden;
            sj = src[eid];
        }
        for (int j = 0; j < cnt; j++) {
            float a = __shfl(al, j, 64);
            int   s = __shfl(sj, j, 64);
            if (lane < F) acc += a * H[(long)s * F + lane];
        }
    }
    if (lane < F) out[node * OS + lane] = acc + bias[lane];
}

// ---------------- CSR build ----------------
__global__ void hist_kernel(const int* __restrict__ dst, int* __restrict__ deg)
{
    for (long e = (long)blockIdx.x * 256 + threadIdx.x; e < N_EDGES; e += (long)gridDim.x * 256)
        atomicAdd(deg + dst[e], 1);
}

__global__ void scan1(const int* __restrict__ deg, int* __restrict__ rtmp, int* __restrict__ parts)
{
    __shared__ int ls[256];
    int t = threadIdx.x;
    long i = (long)blockIdx.x * 256 + t;
    int v = (i < N_NODES) ? deg[i] : 0;
    ls[t] = v; __syncthreads();
    for (int o = 1; o < 256; o <<= 1) {
        int y = (t >= o) ? ls[t - o] : 0;
        __syncthreads();
        ls[t] += y;
        __syncthreads();
    }
    if (i < N_NODES) rtmp[i] = ls[t] - v;
    if (t == 255) parts[blockIdx.x] = ls[255];
}

__global__ void scan2(int* __restrict__ parts, int nb, int* __restrict__ total_out)
{
    __shared__ int ls[512];
    int t = threadIdx.x;
    int v = (t < nb) ? parts[t] : 0;
    ls[t] = v; __syncthreads();
    for (int o = 1; o < 512; o <<= 1) {
        int y = (t >= o) ? ls[t - o] : 0;
        __syncthreads();
        ls[t] += y;
        __syncthreads();
    }
    if (t < nb) parts[t] = ls[t] - v;
    if (t == 0) total_out[0] = ls[511];
}

__global__ void scan3(const int* __restrict__ rtmp, const int* __restrict__ parts,
                      int* __restrict__ rstart, int* __restrict__ cursor)
{
    long i = (long)blockIdx.x * 256 + threadIdx.x;
    if (i < N_NODES) {
        int v = rtmp[i] + parts[i >> 8];
        rstart[i] = v;
        cursor[i] = v;
    }
}

__global__ void scatter_k(const int* __restrict__ dst, int* __restrict__ cursor,
                          int* __restrict__ csr)
{
    for (long e = (long)blockIdx.x * 256 + threadIdx.x; e < N_EDGES; e += (long)gridDim.x * 256) {
        int pos = atomicAdd(cursor + dst[e], 1);
        csr[pos] = (int)e;
    }
}

// ---------------- host helpers ----------------
static void run_dense_block(hipStream_t stream, float* X, int S, int C0,
                            const float* convW, int WS,
                            const float* gamma, const float* beta,
                            float* gsum, float* gsq, float* Aab, float* Bab)
{
    hipMemsetAsync(gsum, 0, 264 * sizeof(float), stream);  // gsum[132] + gsq[132]
    bn_stats<<<256, 256, 0, stream>>>(X, S, 0, C0, gsum, gsq);
    for (int i = 0; i < 6; i++) {
        int C = C0 + 12 * i;
        bn_finalize<<<1, 256, 0, stream>>>(gsum, gsq, gamma + i * WS, beta + i * WS, Aab, Bab, C);
        dense_conv<<<NODE_GRID, 256, 0, stream>>>(X, S, C, convW + (size_t)i * 12 * WS, WS,
                                                  Aab, Bab, gsum, gsq);
    }
}

static void run_gat(hipStream_t stream, const float* Xin, int K,
                    const float* W, const float* a, const float* bias, int F,
                    float* hbuf, float* outbuf, int OS,
                    const int* src, const int* dst,
                    float* sd, float* ss, unsigned* m_u, float* den,
                    float* ev, float* exv, const int* rstart, const int* csr)
{
    gemm_rows<1><<<GEMM_GRID, 256, 0, stream>>>(Xin, W, nullptr, hbuf, K, F, F, 1.0f);
    gat_scores<<<NODE_GRID, 256, 0, stream>>>(hbuf, F, a, sd, ss);
    gat_init<<<NODE_GRID, 256, 0, stream>>>(m_u, den);
    gat_edge1<<<2048, 256, 0, stream>>>(src, dst, sd, ss, ev, m_u);
    gat_fixm<<<NODE_GRID, 256, 0, stream>>>(m_u);
    gat_edge2<<<2048, 256, 0, stream>>>(dst, ev, (const float*)m_u, exv, den);
    gat_aggregate<<<(N_NODES + 3) / 4, 256, 0, stream>>>(src, exv, den, rstart, csr,
                                                         hbuf, F, bias, outbuf, OS);
}

extern "C" void kernel_launch(void* const* d_in, const int* in_sizes, int n_in,
                              void* d_out, int out_size, void* d_ws, size_t ws_size,
                              hipStream_t stream)
{
    const float* x     = (const float*)d_in[0];
    const int*   src   = (const int*)d_in[1];
    const int*   dst   = (const int*)d_in[2];
    const float* w1    = (const float*)d_in[3];
    const float* b1    = (const float*)d_in[4];
    const float* w2    = (const float*)d_in[5];
    const float* b2    = (const float*)d_in[6];
    const float* w3    = (const float*)d_in[7];
    const float* b3    = (const float*)d_in[8];
    const float* conv1 = (const float*)d_in[9];
    const float* bn1g  = (const float*)d_in[10];
    const float* bn1b  = (const float*)d_in[11];
    const float* g1w   = (const float*)d_in[12];
    const float* g1a   = (const float*)d_in[13];
    const float* g1b   = (const float*)d_in[14];
    const float* conv2 = (const float*)d_in[15];
    const float* bn2g  = (const float*)d_in[16];
    const float* bn2b  = (const float*)d_in[17];
    const float* g2w   = (const float*)d_in[18];
    const float* g2a   = (const float*)d_in[19];
    const float* g2b   = (const float*)d_in[20];
    const float* conv3 = (const float*)d_in[21];
    const float* bn3g  = (const float*)d_in[22];
    const float* bn3b  = (const float*)d_in[23];
    float* out = (float*)d_out;

    char* ws = (char*)d_ws;
    size_t off = 0;
    auto alloc = [&](size_t bytes) -> void* {
        void* p = ws + off;
        off += (bytes + 255) & ~(size_t)255;
        return p;
    };
    float*    h      = (float*)alloc((size_t)N_NODES * 256 * 4); // h1/h2 in-place; later gat1h+xcat2
    float*    xcat1  = (float*)alloc((size_t)N_NODES * 96 * 4);  // dense block 1; later gat2h
    float*    ev     = (float*)alloc((size_t)N_EDGES * 4);
    float*    exv    = (float*)alloc((size_t)N_EDGES * 4);
    int*      csr    = (int*)alloc((size_t)N_EDGES * 4);
    int*      deg    = (int*)alloc((size_t)N_NODES * 4);
    int*      rtmp   = (int*)alloc((size_t)N_NODES * 4);
    int*      rstart = (int*)alloc((size_t)(N_NODES + 1) * 4);
    int*      cursor = (int*)alloc((size_t)N_NODES * 4);
    int*      parts  = (int*)alloc(2048);
    unsigned* m_u    = (unsigned*)alloc((size_t)N_NODES * 4);
    float*    den    = (float*)alloc((size_t)N_NODES * 4);
    float*    sd     = (float*)alloc((size_t)N_NODES * 4);
    float*    ss     = (float*)alloc((size_t)N_NODES * 4);
    float*    gsum   = (float*)alloc(264 * 4);
    float*    gsq    = gsum + 132;
    float*    Aab    = (float*)alloc(132 * 4);
    float*    Bab    = (float*)alloc(132 * 4);

    float* gat1h = h;                                      // [N,48] = 19.2 MB
    float* xcat2 = (float*)((char*)h + 19200000);          // [N,120] = 48 MB, disjoint from gat1h
    float* gat2h = xcat1;                                  // [N,60] fits in 38.4 MB

    // ---- CSR by dst (shared by both GATs) ----
    hipMemsetAsync(deg, 0, (size_t)N_NODES * 4, stream);
    hist_kernel<<<2048, 256, 0, stream>>>(dst, deg);
    scan1<<<NODE_GRID, 256, 0, stream>>>(deg, rtmp, parts);
    scan2<<<1, 512, 0, stream>>>(parts, NODE_GRID, rstart + N_NODES);
    scan3<<<NODE_GRID, 256, 0, stream>>>(rtmp, parts, rstart, cursor);
    scatter_k<<<2048, 256, 0, stream>>>(dst, cursor, csr);

    // ---- MLP ----
    gemm_rows<4><<<GEMM_GRID, 256, 0, stream>>>(x, w1, b1, h,     64,  256, 256, 0.01f);
    gemm_rows<4><<<GEMM_GRID, 256, 0, stream>>>(h, w2, b2, h,     256, 256, 256, 0.01f); // in-place
    gemm_rows<1><<<GEMM_GRID, 256, 0, stream>>>(h, w3, b3, xcat1, 256, 24,  96,  0.01f);

    // ---- dense block 1 (24 -> 96) ----
    run_dense_block(stream, xcat1, 96, 24, conv1, 84, bn1g, bn1b, gsum, gsq, Aab, Bab);

    // ---- GAT 1 (96 -> 48) ----
    run_gat(stream, xcat1, 96, g1w, g1a, g1b, 48, gat1h, xcat2, 120,
            src, dst, sd, ss, m_u, den, ev, exv, rstart, csr);

    // ---- dense block 2 (48 -> 120) ----
    run_dense_block(stream, xcat2, 120, 48, conv2, 108, bn2g, bn2b, gsum, gsq, Aab, Bab);

    // ---- GAT 2 (120 -> 60) ----
    run_gat(stream, xcat2, 120, g2w, g2a, g2b, 60, gat2h, out, 132,
            src, dst, sd, ss, m_u, den, ev, exv, rstart, csr);

    // ---- dense block 3 (60 -> 132) writes directly into d_out ----
    run_dense_block(stream, out, 132, 60, conv3, 120, bn3g, bn3b, gsum, gsq, Aab, Bab);
}